// Round 5
// baseline (69.544 us; speedup 1.0000x reference)
//
#include <hip/hip_runtime.h>

#define DENSE_L 20
#define LT 16
#define RPT 2          // rows per thread
#define BLOCK 256
#define TCHUNK 4       // t-values per streamed chunk (one float4 of x per row)
#define NCHUNK (DENSE_L / TCHUNK)   // 5

typedef float v4f  __attribute__((ext_vector_type(4)));
typedef float v16f __attribute__((ext_vector_type(16)));

// Tiny precompute: G[t][k] = exp(-(t+1-w_k)^2/std^2) into workspace.
// 320 floats; 1 block. Runs on the same stream before the main kernel.
__global__ void g_precompute(const float* __restrict__ weight, float* __restrict__ G)
{
    int i = threadIdx.x;            // 320 threads = 5 waves
    if (i < DENSE_L * LT) {
        int t = i >> 4;             // i / 16
        int k = i & 15;             // i % 16
        float d = (float)(t + 1) - weight[k];
        G[i] = __expf(-d * d * 6.25f);   // 1/std^2 = 6.25
    }
}

// R0-R4 lesson: 40 x-floats + 32 acc + 16 G VGPRs can't fit under 128 without
// spilling (R3/R4), and at 208 VGPR we starve (R0). Fix the STRUCTURE: G is
// wave-uniform -> load it via uniform (scalar) loads into SGPRs from the
// precomputed table. Frees 16 VGPRs AND deletes 80 ds_read_b128/wave of LDS
// traffic. FMA is v_fmac_f32 v,s,v (1 SGPR operand = legal). Natural live set
// ~60 VGPR -> 5-6 waves/SIMD, no launch-bounds pressure, no spill.
__global__ __launch_bounds__(BLOCK) void sampling_kernel(
    const float* __restrict__ x, const float* __restrict__ Gw,
    float* __restrict__ out, int nrows)
{
    int row0 = blockIdx.x * (BLOCK * RPT) + threadIdx.x;
    int row1 = row0 + BLOCK;
    bool v0 = (row0 < nrows), v1 = (row1 < nrows);
    int r0c = v0 ? row0 : (nrows - 1);   // clamped: loads always safe
    int r1c = v1 ? row1 : (nrows - 1);

    const float4* p0 = reinterpret_cast<const float4*>(x + (size_t)r0c * DENSE_L);
    const float4* p1 = reinterpret_cast<const float4*>(x + (size_t)r1c * DENSE_L);

    float a0[LT], a1[LT];
    #pragma unroll
    for (int k = 0; k < LT; ++k) { a0[k] = 0.f; a1[k] = 0.f; }

    // 1-deep prefetch pipeline over 5 chunks of 4 t-values
    float4 xa = p0[0];
    float4 xb = p1[0];

    #pragma unroll 1
    for (int c = 0; c < NCHUNK; ++c) {
        // Uniform 64B loads -> s_load_dwordx16 (address has no lane dependence;
        // all pointers __restrict__ so the loads can scalarize).
        const v16f* gp = reinterpret_cast<const v16f*>(Gw + c * (TCHUNK * LT));
        v16f g0 = gp[0], g1 = gp[1], g2 = gp[2], g3 = gp[3];

        int cn = (c + 1 < NCHUNK) ? c + 1 : c;   // clamped redundant last load (L1 hit)
        float4 na = p0[cn];
        float4 nb = p1[cn];

        float xs0[TCHUNK] = {xa.x, xa.y, xa.z, xa.w};
        float xs1[TCHUNK] = {xb.x, xb.y, xb.z, xb.w};
        v16f  gs[TCHUNK]  = {g0, g1, g2, g3};

        #pragma unroll
        for (int tt = 0; tt < TCHUNK; ++tt) {
            #pragma unroll
            for (int k = 0; k < LT; ++k) a0[k] += xs0[tt] * gs[tt][k];
            #pragma unroll
            for (int k = 0; k < LT; ++k) a1[k] += xs1[tt] * gs[tt][k];
        }

        xa = na;
        xb = nb;
    }

    if (v0) {
        float4* o = reinterpret_cast<float4*>(out + (size_t)row0 * LT);
        o[0] = make_float4(a0[0], a0[1], a0[2], a0[3]);
        o[1] = make_float4(a0[4], a0[5], a0[6], a0[7]);
        o[2] = make_float4(a0[8], a0[9], a0[10], a0[11]);
        o[3] = make_float4(a0[12], a0[13], a0[14], a0[15]);
    }
    if (v1) {
        float4* o = reinterpret_cast<float4*>(out + (size_t)row1 * LT);
        o[0] = make_float4(a1[0], a1[1], a1[2], a1[3]);
        o[1] = make_float4(a1[4], a1[5], a1[6], a1[7]);
        o[2] = make_float4(a1[8], a1[9], a1[10], a1[11]);
        o[3] = make_float4(a1[12], a1[13], a1[14], a1[15]);
    }
}

extern "C" void kernel_launch(void* const* d_in, const int* in_sizes, int n_in,
                              void* d_out, int out_size, void* d_ws, size_t ws_size,
                              hipStream_t stream) {
    const float* x = (const float*)d_in[0];
    const float* w = (const float*)d_in[1];
    float* out = (float*)d_out;
    float* G = (float*)d_ws;                 // 320 floats = 1280 B of workspace
    int nrows = in_sizes[0] / DENSE_L;       // 1,048,576

    g_precompute<<<1, 320, 0, stream>>>(w, G);

    int grid = (nrows + BLOCK * RPT - 1) / (BLOCK * RPT);
    sampling_kernel<<<grid, BLOCK, 0, stream>>>(x, G, out, nrows);
}

// Round 6
// 43.276 us; speedup vs baseline: 1.6070x; 1.6070x over previous
//
#include <hip/hip_runtime.h>

#define DENSE_L 20
#define LT 16
#define RPT 2                  // rows per thread
#define BLOCK 256
#define KQ 4                   // k-outputs per pass (quarter)
#define NPASS (LT / KQ)        // 4 passes
#define GPP (DENSE_L * KQ)     // 80 G floats per pass = 5 x 64B uniform loads

typedef float v4f  __attribute__((ext_vector_type(4)));
typedef float v16f __attribute__((ext_vector_type(16)));

// Precompute G TRANSPOSED: Gt[k*20 + t] = exp(-((t+1)-w_k)^2 / std^2).
// k-major so each k-quarter is 80 contiguous floats (64B-aligned: 320B stride).
__global__ void g_precompute(const float* __restrict__ weight, float* __restrict__ Gt)
{
    int i = threadIdx.x;               // 320 threads
    if (i < DENSE_L * LT) {
        int k = i / DENSE_L;
        int t = i - k * DENSE_L;
        float d = (float)(t + 1) - weight[k];
        Gt[i] = __expf(-d * d * 6.25f);    // 1/std^2 = 6.25
    }
}

// Synthesis of 5 rounds of evidence:
//  - R0: bulk back-to-back x loads -> best FETCH (41MB) and best time. Keep.
//  - R4/R5: chunked x streaming -> HBM re-fetch (53/145MB) + per-chunk stalls. Drop.
//  - R5: uniform loads of precomputed G scalarize (SGPR 96) freeing VGPR+LDS. Keep.
//  - R2/R3: launch_bounds min-waves hint -> allocator spills. Avoid.
//  - ~102 SGPR/wave cap -> G must come in k-quarters (80 SGPRs live/pass).
// Live set: xv 40 + acc 8 + addr ~10 => ~60 VGPR, 0 LDS -> ~8 waves/SIMD.
__global__ __launch_bounds__(BLOCK) void sampling_kernel(
    const float* __restrict__ x, const float* __restrict__ Gt,
    float* __restrict__ out, int nrows)
{
    int row0 = blockIdx.x * (BLOCK * RPT) + threadIdx.x;
    int row1 = row0 + BLOCK;
    bool v0 = (row0 < nrows), v1 = (row1 < nrows);
    int r0c = v0 ? row0 : (nrows - 1);   // clamped: loads always in-bounds
    int r1c = v1 ? row1 : (nrows - 1);

    // Bulk load both rows: 10 float4 back-to-back (max MLP, one tight
    // time-window per cache line -> no HBM sector re-fetch).
    float xv0[DENSE_L], xv1[DENSE_L];
    {
        const float4* p = reinterpret_cast<const float4*>(x + (size_t)r0c * DENSE_L);
        #pragma unroll
        for (int j = 0; j < DENSE_L / 4; ++j) {
            float4 v = p[j];
            xv0[4*j+0] = v.x; xv0[4*j+1] = v.y; xv0[4*j+2] = v.z; xv0[4*j+3] = v.w;
        }
    }
    {
        const float4* p = reinterpret_cast<const float4*>(x + (size_t)r1c * DENSE_L);
        #pragma unroll
        for (int j = 0; j < DENSE_L / 4; ++j) {
            float4 v = p[j];
            xv1[4*j+0] = v.x; xv1[4*j+1] = v.y; xv1[4*j+2] = v.z; xv1[4*j+3] = v.w;
        }
    }

    float* o0 = out + (size_t)row0 * LT;
    float* o1 = out + (size_t)row1 * LT;

    // 4 k-quarter passes; rolled so only one quarter's G (80 SGPRs) is live.
    #pragma unroll 1
    for (int p = 0; p < NPASS; ++p) {
        // Uniform address (no lane dependence) -> scalar loads into SGPRs (K$-hot).
        const v16f* gp = reinterpret_cast<const v16f*>(Gt + p * GPP);
        v16f q0 = gp[0], q1 = gp[1], q2 = gp[2], q3 = gp[3], q4 = gp[4];
        v16f q[5] = {q0, q1, q2, q3, q4};

        float a0[KQ] = {0.f, 0.f, 0.f, 0.f};
        float a1[KQ] = {0.f, 0.f, 0.f, 0.f};

        #pragma unroll
        for (int kk = 0; kk < KQ; ++kk) {
            #pragma unroll
            for (int t = 0; t < DENSE_L; ++t) {
                int gi = kk * DENSE_L + t;          // compile-time after unroll
                float g = q[gi >> 4][gi & 15];      // static vector subscript
                a0[kk] += xv0[t] * g;               // v_fmac v, s, v (1 SGPR: legal)
                a1[kk] += xv1[t] * g;
            }
        }

        if (v0) *reinterpret_cast<float4*>(o0 + p * KQ) = make_float4(a0[0], a0[1], a0[2], a0[3]);
        if (v1) *reinterpret_cast<float4*>(o1 + p * KQ) = make_float4(a1[0], a1[1], a1[2], a1[3]);
    }
}

extern "C" void kernel_launch(void* const* d_in, const int* in_sizes, int n_in,
                              void* d_out, int out_size, void* d_ws, size_t ws_size,
                              hipStream_t stream) {
    const float* x = (const float*)d_in[0];
    const float* w = (const float*)d_in[1];
    float* out = (float*)d_out;
    float* Gt = (float*)d_ws;                // 320 floats = 1280 B workspace
    int nrows = in_sizes[0] / DENSE_L;       // 1,048,576

    g_precompute<<<1, 320, 0, stream>>>(w, Gt);

    int grid = (nrows + BLOCK * RPT - 1) / (BLOCK * RPT);
    sampling_kernel<<<grid, BLOCK, 0, stream>>>(x, Gt, out, nrows);
}